// Round 1
// baseline (7086.629 us; speedup 1.0000x reference)
//
#include <hip/hip_runtime.h>
#include <hip/hip_bf16.h>

#define DINL __device__ __forceinline__

namespace {

constexpr int Tn = 256;   // sequence length
constexpr int Bn = 64;    // batch
constexpr int En = 300;   // embedding dim
constexpr int HDn = 256;  // per-direction hidden
constexpr int Kt = 20;    // tagset
constexpr int STOPt = 19;
constexpr int STARTt = 18;
constexpr float NEGV = -10000.0f;

// LSTM decomposition: 2 dirs x 4 batch-groups(16) x 16 slices(16 hidden cols) = 128 blocks
constexpr int SLICES = 16;
constexpr int BGROUPS = 4;
constexpr int BGSZ = 16;
constexpr int SCOLS = HDn / SLICES;   // 16 hidden cols per slice
constexpr int SROWS = 4 * SCOLS;      // 64 gate rows per slice

DINL float sigm(float x) { return 1.0f / (1.0f + __expf(-x)); }
DINL float tanh_f(float x) {
  float ax = fabsf(x);
  float e = __expf(-2.0f * ax);       // in (0,1]
  float t = (1.0f - e) / (1.0f + e);
  return x < 0.0f ? -t : t;
}

// ---------------- K0: zero the dataflow flags (ws is poisoned 0xAA) ----------
__global__ void k_init(int* flags) {
  int i = threadIdx.x;
  if (i < 128) flags[i] = 0;
}

// ---------------- K1: transpose/concat W_ih into Wt[300][2048] ---------------
__global__ void k_wt(const float* __restrict__ wf, const float* __restrict__ wb,
                     float* __restrict__ Wt) {
  int idx = blockIdx.x * 256 + threadIdx.x;
  if (idx >= 300 * 2048) return;
  int k = idx >> 11, n = idx & 2047;
  const float* w = (n < 1024) ? wf : wb;
  int nn = n & 1023;
  Wt[idx] = w[nn * 300 + k];
}

// ---------------- K2: x_proj = gather(embeds) @ W_ih^T + b -------------------
// C[16384, 2048], row m = t*64 + b. Tile 64(M) x 128(N), BK=20, 256 threads.
__global__ __launch_bounds__(256) void k_xproj(
    const int* __restrict__ sentence, const float* __restrict__ table,
    const float* __restrict__ Wt, const float* __restrict__ b_f,
    const float* __restrict__ b_b, float* __restrict__ xproj) {
  __shared__ float As[20][68];    // A^T tile: [kk][row(b)]
  __shared__ float Bs[20][136];   // [kk][col]
  __shared__ int tok[64];

  int tid = threadIdx.x;
  int t = blockIdx.x;             // one time index per M-tile (64 rows = 64 b)
  int n0 = blockIdx.y * 128;

  if (tid < 64) tok[tid] = sentence[tid * Tn + t];  // sentence[b][t]
  __syncthreads();

  int ty = tid >> 4, tx = tid & 15;   // 16x16 threads; micro-tile 4(M) x 8(N)
  float acc[4][8];
#pragma unroll
  for (int i = 0; i < 4; ++i)
#pragma unroll
    for (int j = 0; j < 8; ++j) acc[i][j] = 0.0f;

  for (int k0 = 0; k0 < 300; k0 += 20) {
    // A tile: 64 rows x 20 k (gathered embedding rows)
#pragma unroll
    for (int i = 0; i < 5; ++i) {
      int idx = i * 256 + tid;        // 0..1279
      int r = idx / 20, kk = idx % 20;
      As[kk][r] = table[tok[r] * 300 + k0 + kk];
    }
    // B tile: 20 k x 128 n (from pre-transposed Wt, coalesced)
#pragma unroll
    for (int i = 0; i < 10; ++i) {
      int idx = i * 256 + tid;        // 0..2559
      int kk = idx >> 7, c = idx & 127;
      Bs[kk][c] = Wt[(k0 + kk) * 2048 + n0 + c];
    }
    __syncthreads();
#pragma unroll
    for (int kk = 0; kk < 20; ++kk) {
      float4 a4 = *(const float4*)&As[kk][ty * 4];
      float4 b4a = *(const float4*)&Bs[kk][tx * 8];
      float4 b4b = *(const float4*)&Bs[kk][tx * 8 + 4];
      float av[4] = {a4.x, a4.y, a4.z, a4.w};
      float bvv[8] = {b4a.x, b4a.y, b4a.z, b4a.w, b4b.x, b4b.y, b4b.z, b4b.w};
#pragma unroll
      for (int i = 0; i < 4; ++i)
#pragma unroll
        for (int j = 0; j < 8; ++j) acc[i][j] += av[i] * bvv[j];
    }
    __syncthreads();
  }

  float bias[8];
#pragma unroll
  for (int j = 0; j < 8; ++j) {
    int n = n0 + tx * 8 + j;
    bias[j] = (n < 1024) ? b_f[n] : b_b[n - 1024];
  }
#pragma unroll
  for (int i = 0; i < 4; ++i) {
    size_t m = (size_t)t * 64 + ty * 4 + i;   // row = (t, b=ty*4+i)
    float* dst = &xproj[m * 2048 + n0 + tx * 8];
    float4 v0 = {acc[i][0] + bias[0], acc[i][1] + bias[1], acc[i][2] + bias[2],
                 acc[i][3] + bias[3]};
    float4 v1 = {acc[i][4] + bias[4], acc[i][5] + bias[5], acc[i][6] + bias[6],
                 acc[i][7] + bias[7]};
    *(float4*)dst = v0;
    *(float4*)(dst + 4) = v1;
  }
}

// ---------------- K3: persistent bidirectional LSTM --------------------------
// 128 blocks x 512 thr. Block (gid = bid&7 -> dir,bg ; s = bid>>3).
// W slice (64 gate rows x 256) stationary in LDS; h exchanged via h_all in ws,
// ordered by per-producer monotonic flags (agent-scope acquire/release).
__global__ __launch_bounds__(512) void k_lstm(
    const float* __restrict__ whh_f, const float* __restrict__ whh_b,
    const float* __restrict__ xproj, float* __restrict__ h_all, int* flags) {
  __shared__ float Wl[SROWS * HDn];     // 64*256 f32, XOR-swizzled granules
  __shared__ float hl[BGSZ * HDn];      // 16*256 f32, XOR-swizzled granules
  __shared__ float gl[BGSZ][SROWS + 4]; // gates scratch [16][68]

  int tid = threadIdx.x;
  int bid = blockIdx.x;
  int gid = bid & 7;        // group (same-XCD affine): dir = gid>>2, bg = gid&3
  int s = bid >> 3;         // slice 0..15
  int dir = gid >> 2;
  int bg = gid & 3;
  const float* whh = dir ? whh_b : whh_f;

  // --- preload W slice (local row r = g*16+c  <->  global row g*256+s*16+c)
  {
    int pr = tid >> 3;           // 0..63
    int kq = tid & 7;
    int g = pr >> 4, c = pr & 15;
    const float* src = whh + (g * 256 + s * 16 + c) * 256 + kq * 32;
    int rsw = pr & 7;
#pragma unroll 8
    for (int kk = 0; kk < 32; ++kk) {
      int k = kq * 32 + kk;
      Wl[pr * 256 + 4 * ((k >> 2) ^ rsw) + (k & 3)] = src[kk];
    }
  }

  int lane = tid & 63, wv = tid >> 6;
  int bb = lane & 15, rj = lane >> 4;
  int wbase = wv * 8;
  int r0 = wbase + rj * 2, r1 = r0 + 1;
  int hsw = bb & 7, w0sw = r0 & 7, w1sw = r1 & 7;
  int ub = tid >> 4, ucol = tid & 15;     // update-phase mapping (tid<256)
  float c_reg = 0.0f;
  __syncthreads();

  for (int st = 0; st < Tn; ++st) {
    int xt = dir ? (Tn - 1 - st) : st;

    // prefetch x-projection gates (independent of flags -> overlaps the spin)
    float xp0 = 0, xp1 = 0, xp2 = 0, xp3 = 0;
    if (tid < 256) {
      size_t base = ((size_t)(xt * 64 + bg * 16 + ub)) * 2048 + dir * 1024 +
                    s * 16 + ucol;
      xp0 = xproj[base];
      xp1 = xproj[base + 256];
      xp2 = xproj[base + 512];
      xp3 = xproj[base + 768];
    }

    float acc0 = 0.0f, acc1 = 0.0f;
    if (st > 0) {
      if (tid < 16) {
        int fi = gid * 16 + tid;
        while (__hip_atomic_load(&flags[fi], __ATOMIC_ACQUIRE,
                                 __HIP_MEMORY_SCOPE_AGENT) < st) {
        }
      }
      __syncthreads();
      int pt = dir ? (xt + 1) : (xt - 1);
      const float* hsrc = h_all + ((size_t)(dir * Tn + pt) * 64 + bg * 16) * 256;
#pragma unroll
      for (int i = 0; i < 8; ++i) {
        int idx = i * 512 + tid;       // 0..4095
        int hb = idx >> 8, k = idx & 255;
        hl[hb * 256 + 4 * ((k >> 2) ^ (hb & 7)) + (k & 3)] = hsrc[idx];
      }
      __syncthreads();
#pragma unroll 4
      for (int kg = 0; kg < 64; ++kg) {
        float4 hv = *(const float4*)&hl[bb * 256 + 4 * (kg ^ hsw)];
        float4 w0 = *(const float4*)&Wl[r0 * 256 + 4 * (kg ^ w0sw)];
        float4 w1 = *(const float4*)&Wl[r1 * 256 + 4 * (kg ^ w1sw)];
        acc0 += hv.x * w0.x + hv.y * w0.y + hv.z * w0.z + hv.w * w0.w;
        acc1 += hv.x * w1.x + hv.y * w1.y + hv.z * w1.z + hv.w * w1.w;
      }
    }
    gl[bb][r0] = acc0;
    gl[bb][r1] = acc1;
    __syncthreads();

    if (tid < 256) {
      float gi = gl[ub][0 * 16 + ucol] + xp0;
      float gf = gl[ub][1 * 16 + ucol] + xp1;
      float gg = gl[ub][2 * 16 + ucol] + xp2;
      float go = gl[ub][3 * 16 + ucol] + xp3;
      c_reg = sigm(gf) * c_reg + sigm(gi) * tanh_f(gg);
      float h = sigm(go) * tanh_f(c_reg);
      h_all[((size_t)(dir * Tn + xt) * 64 + bg * 16 + ub) * 256 + s * 16 +
            ucol] = h;
    }
    __threadfence();   // make h stores agent-visible before publishing
    __syncthreads();
    if (tid == 0) {
      __hip_atomic_store(&flags[gid * 16 + s], st + 1, __ATOMIC_RELEASE,
                         __HIP_MEMORY_SCOPE_AGENT);
    }
    __syncthreads();   // keep gl/hl reads of this step ahead of next rewrites
  }
}

// ---------------- K4: feats = concat(hf,hb) @ W_out^T + b_out ----------------
// one block per t; 256 thr = 64 b x 4 k-groups(5)
__global__ __launch_bounds__(256) void k_feats(const float* __restrict__ h_all,
                                               const float* __restrict__ Wout,
                                               const float* __restrict__ bout,
                                               float* __restrict__ feats) {
  __shared__ float Wl[20 * 512];   // 40KB
  __shared__ float hlf[64 * 256];  // 64KB, XOR-swizzled

  int tid = threadIdx.x;
  int t = blockIdx.x;
  for (int i = tid; i < 20 * 512; i += 256) Wl[i] = Wout[i];

  float acc[5] = {0, 0, 0, 0, 0};
  int b = tid & 63, kg5 = tid >> 6;
  int swz = b & 7;

  for (int d = 0; d < 2; ++d) {
    __syncthreads();
    const float* hsrc = h_all + ((size_t)(d * Tn + t)) * 64 * 256;
#pragma unroll 8
    for (int i = 0; i < 64; ++i) {
      int idx = i * 256 + tid;
      int hb = idx >> 8, k = idx & 255;
      hlf[hb * 256 + 4 * ((k >> 2) ^ (hb & 7)) + (k & 3)] = hsrc[idx];
    }
    __syncthreads();
    for (int jg = 0; jg < 64; ++jg) {
      float4 hv = *(const float4*)&hlf[b * 256 + 4 * (jg ^ swz)];
#pragma unroll
      for (int kk = 0; kk < 5; ++kk) {
        int krow = kg5 * 5 + kk;
        float4 wvv = *(const float4*)&Wl[krow * 512 + d * 256 + jg * 4];
        acc[kk] += hv.x * wvv.x + hv.y * wvv.y + hv.z * wvv.z + hv.w * wvv.w;
      }
    }
  }
#pragma unroll
  for (int kk = 0; kk < 5; ++kk) {
    int krow = kg5 * 5 + kk;
    feats[((size_t)b * Tn + t) * Kt + krow] = acc[kk] + bout[krow];
  }
}

// ---------------- K5: Viterbi decode, one wave per batch element -------------
__global__ __launch_bounds__(64) void k_viterbi(const float* __restrict__ feats,
                                                const float* __restrict__ trans,
                                                const int* __restrict__ length,
                                                float* __restrict__ out) {
  __shared__ float tr[400];
  __shared__ float fv[20];
  __shared__ float term[20];
  __shared__ unsigned char bps[256][20];

  int b = blockIdx.x;
  int lane = threadIdx.x;
  for (int i = lane; i < 400; i += 64) tr[i] = trans[i];
  if (lane < 20) fv[lane] = (lane == STARTt) ? 0.0f : NEGV;
  int len = length[b];
  __syncthreads();

  for (int t = 0; t < Tn; ++t) {
    float nf = 0.0f;
    int bp = 0;
    if (lane < 20) {
      if (t < len) {
        float vmax = -3.4e38f;
        int pb = 0;
#pragma unroll
        for (int p = 0; p < 20; ++p) {
          float v = fv[p] + tr[lane * 20 + p];
          if (v > vmax) { vmax = v; pb = p; }   // strict > == first-argmax
        }
        nf = vmax + feats[((size_t)b * Tn + t) * Kt + lane];
        bp = pb;
      } else {
        nf = fv[lane];
        bp = lane;
      }
    }
    __syncthreads();
    if (lane < 20) {
      fv[lane] = nf;
      bps[t][lane] = (unsigned char)bp;
    }
    __syncthreads();
  }

  if (lane < 20) term[lane] = fv[lane] + tr[STOPt * 20 + lane];
  __syncthreads();
  if (lane == 0) {
    float smax = term[0];
    int last = 0;
    for (int p = 1; p < 20; ++p)
      if (term[p] > smax) { smax = term[p]; last = p; }
    out[b] = smax;                     // viterbi score
    int tag = last;
    for (int t = Tn - 1; t >= 0; --t) {
      out[64 + b * Tn + t] = (float)tag;
      tag = bps[t][tag];
    }
  }
}

}  // namespace

extern "C" void kernel_launch(void* const* d_in, const int* in_sizes, int n_in,
                              void* d_out, int out_size, void* d_ws,
                              size_t ws_size, hipStream_t stream) {
  const int* sentence = (const int*)d_in[0];
  const int* length = (const int*)d_in[1];
  const float* table = (const float*)d_in[2];
  const float* w_ih_f = (const float*)d_in[3];
  const float* w_hh_f = (const float*)d_in[4];
  // b_f folded into xproj bias
  const float* b_f = (const float*)d_in[5];
  const float* w_ih_b = (const float*)d_in[6];
  const float* w_hh_b = (const float*)d_in[7];
  const float* b_b = (const float*)d_in[8];
  const float* W_out = (const float*)d_in[9];
  const float* b_out = (const float*)d_in[10];
  const float* trans = (const float*)d_in[11];
  float* out = (float*)d_out;

  // workspace layout (floats)
  float* ws = (float*)d_ws;
  float* xproj = ws;                               // 256*64*2048 = 33,554,432
  float* h_all = xproj + (size_t)Tn * Bn * 2048;   // 2*256*64*256 = 8,388,608
  float* Wt = h_all + (size_t)2 * Tn * Bn * HDn;   // 300*2048     =   614,400
  float* feats = Wt + (size_t)300 * 2048;          // 64*256*20    =   327,680
  int* flags = (int*)(feats + (size_t)Bn * Tn * Kt);  // 128 ints
  (void)ws_size; (void)in_sizes; (void)n_in; (void)out_size;

  k_init<<<dim3(1), dim3(128), 0, stream>>>(flags);
  k_wt<<<dim3(2400), dim3(256), 0, stream>>>(w_ih_f, w_ih_b, Wt);
  k_xproj<<<dim3(256, 16), dim3(256), 0, stream>>>(sentence, table, Wt, b_f,
                                                   b_b, xproj);
  k_lstm<<<dim3(128), dim3(512), 0, stream>>>(w_hh_f, w_hh_b, xproj, h_all,
                                              flags);
  k_feats<<<dim3(256), dim3(256), 0, stream>>>(h_all, W_out, b_out, feats);
  k_viterbi<<<dim3(64), dim3(64), 0, stream>>>(feats, trans, length, out);
}

// Round 2
// 2369.632 us; speedup vs baseline: 2.9906x; 2.9906x over previous
//
#include <hip/hip_runtime.h>
#include <hip/hip_bf16.h>

#define DINL __device__ __forceinline__

namespace {

constexpr int Tn = 256;   // sequence length
constexpr int Bn = 64;    // batch
constexpr int HDn = 256;  // per-direction hidden
constexpr int Kt = 20;    // tagset
constexpr int STOPt = 19;
constexpr int STARTt = 18;
constexpr float NEGV = -10000.0f;

DINL float sigm(float x) { return 1.0f / (1.0f + __expf(-x)); }
DINL float tanh_f(float x) {
  float ax = fabsf(x);
  float e = __expf(-2.0f * ax);       // in (0,1]
  float t = (1.0f - e) / (1.0f + e);
  return x < 0.0f ? -t : t;
}

DINL float agent_ld(const float* p) {
  return __hip_atomic_load(p, __ATOMIC_RELAXED, __HIP_MEMORY_SCOPE_AGENT);
}
DINL void agent_st(float* p, float v) {
  __hip_atomic_store(p, v, __ATOMIC_RELAXED, __HIP_MEMORY_SCOPE_AGENT);
}

// ---------------- K0: zero the dataflow flags (ws is poisoned 0xAA) ----------
__global__ void k_init(int* flags) {
  int i = threadIdx.x;
  if (i < 128) flags[i] = 0;
}

// ---------------- K1: transpose/concat W_ih into Wt[300][2048] ---------------
__global__ void k_wt(const float* __restrict__ wf, const float* __restrict__ wb,
                     float* __restrict__ Wt) {
  int idx = blockIdx.x * 256 + threadIdx.x;
  if (idx >= 300 * 2048) return;
  int k = idx >> 11, n = idx & 2047;
  const float* w = (n < 1024) ? wf : wb;
  int nn = n & 1023;
  Wt[idx] = w[nn * 300 + k];
}

// ---------------- K2: x_proj = gather(embeds) @ W_ih^T + b -------------------
// C[16384, 2048], row m = t*64 + b. Tile 64(M) x 128(N), BK=20, 256 threads.
__global__ __launch_bounds__(256) void k_xproj(
    const int* __restrict__ sentence, const float* __restrict__ table,
    const float* __restrict__ Wt, const float* __restrict__ b_f,
    const float* __restrict__ b_b, float* __restrict__ xproj) {
  __shared__ float As[20][68];    // A^T tile: [kk][row(b)]
  __shared__ float Bs[20][136];   // [kk][col]
  __shared__ int tok[64];

  int tid = threadIdx.x;
  int t = blockIdx.x;             // one time index per M-tile (64 rows = 64 b)
  int n0 = blockIdx.y * 128;

  if (tid < 64) tok[tid] = sentence[tid * Tn + t];  // sentence[b][t]
  __syncthreads();

  int ty = tid >> 4, tx = tid & 15;   // 16x16 threads; micro-tile 4(M) x 8(N)
  float acc[4][8];
#pragma unroll
  for (int i = 0; i < 4; ++i)
#pragma unroll
    for (int j = 0; j < 8; ++j) acc[i][j] = 0.0f;

  for (int k0 = 0; k0 < 300; k0 += 20) {
    // A tile: 64 rows x 20 k (gathered embedding rows)
#pragma unroll
    for (int i = 0; i < 5; ++i) {
      int idx = i * 256 + tid;        // 0..1279
      int r = idx / 20, kk = idx % 20;
      As[kk][r] = table[tok[r] * 300 + k0 + kk];
    }
    // B tile: 20 k x 128 n (from pre-transposed Wt, coalesced)
#pragma unroll
    for (int i = 0; i < 10; ++i) {
      int idx = i * 256 + tid;        // 0..2559
      int kk = idx >> 7, c = idx & 127;
      Bs[kk][c] = Wt[(k0 + kk) * 2048 + n0 + c];
    }
    __syncthreads();
#pragma unroll
    for (int kk = 0; kk < 20; ++kk) {
      float4 a4 = *(const float4*)&As[kk][ty * 4];
      float4 b4a = *(const float4*)&Bs[kk][tx * 8];
      float4 b4b = *(const float4*)&Bs[kk][tx * 8 + 4];
      float av[4] = {a4.x, a4.y, a4.z, a4.w};
      float bvv[8] = {b4a.x, b4a.y, b4a.z, b4a.w, b4b.x, b4b.y, b4b.z, b4b.w};
#pragma unroll
      for (int i = 0; i < 4; ++i)
#pragma unroll
        for (int j = 0; j < 8; ++j) acc[i][j] += av[i] * bvv[j];
    }
    __syncthreads();
  }

  float bias[8];
#pragma unroll
  for (int j = 0; j < 8; ++j) {
    int n = n0 + tx * 8 + j;
    bias[j] = (n < 1024) ? b_f[n] : b_b[n - 1024];
  }
#pragma unroll
  for (int i = 0; i < 4; ++i) {
    size_t m = (size_t)t * 64 + ty * 4 + i;   // row = (t, b=ty*4+i)
    float* dst = &xproj[m * 2048 + n0 + tx * 8];
    float4 v0 = {acc[i][0] + bias[0], acc[i][1] + bias[1], acc[i][2] + bias[2],
                 acc[i][3] + bias[3]};
    float4 v1 = {acc[i][4] + bias[4], acc[i][5] + bias[5], acc[i][6] + bias[6],
                 acc[i][7] + bias[7]};
    *(float4*)dst = v0;
    *(float4*)(dst + 4) = v1;
  }
}

// ---------------- K3: persistent bidirectional LSTM --------------------------
// 128 blocks x 512 thr. gid = bid&7 -> (dir, batch-group); s = bid>>3 (slice).
// W slice (64 gate rows x 256 k) REGISTER-stationary: thread (row=tid>>3,
// kc=tid&7) holds W[row][kc*32..kc*32+32) = 32 VGPRs. h exchanged via h_all
// with relaxed agent-scope (sc1) atomics + per-slice flags; NO threadfence,
// NO acquire/release (avoids per-step L2 writeback/invalidate).
__global__ __launch_bounds__(512) void k_lstm(
    const float* __restrict__ whh_f, const float* __restrict__ whh_b,
    const float* __restrict__ xproj, float* __restrict__ h_all, int* flags) {
  __shared__ __align__(16) float hl[16 * 256];  // staged h chunk, granule-XOR
  __shared__ float gl[64 * 17];                 // reduced gates [row][b]

  int tid = threadIdx.x;
  int bid = blockIdx.x;
  int gid = bid & 7;        // dir = gid>>2, bg = gid&3 (XCD-affine: perf only)
  int s = bid >> 3;         // slice 0..15 (16 hidden cols each)
  int dir = gid >> 2;
  int bg = gid & 3;
  const float* whh = dir ? whh_b : whh_f;

  int row = tid >> 3;       // local gate row 0..63 (g = row>>4, c = row&15)
  int kc = tid & 7;         // k-chunk of 32
  int g = row >> 4, c = row & 15;

  // --- W slice into registers (one-time, 8 x b128 per thread)
  float w[32];
  {
    const float* src =
        whh + ((size_t)(g * 256 + s * 16 + c)) * 256 + kc * 32;
#pragma unroll
    for (int j = 0; j < 8; ++j) {
      float4 v = *(const float4*)(src + j * 4);
      w[j * 4 + 0] = v.x; w[j * 4 + 1] = v.y;
      w[j * 4 + 2] = v.z; w[j * 4 + 3] = v.w;
    }
  }

  int ub = tid >> 4, ucol = tid & 15;   // update-phase mapping (tid<256)
  float c_reg = 0.0f;

  // staging mapping: 2 granules (float4) per thread
  int g0 = 2 * tid;           // granule id 0..1023
  int sb = g0 >> 6;           // batch row 0..15
  int sq = g0 & 63;           // granule within row (handles sq, sq+1)
  int d0 = (sq & ~7) | ((sq ^ (sq >> 3)) & 7);
  int d1 = ((sq + 1) & ~7) | (((sq + 1) ^ ((sq + 1) >> 3)) & 7);

  int fbase = gid * 16;

  for (int st = 0; st < Tn; ++st) {
    int xt = dir ? (Tn - 1 - st) : st;

    // prefetch x-projection gates (independent of flags -> overlaps the spin)
    float xp0 = 0, xp1 = 0, xp2 = 0, xp3 = 0;
    if (tid < 256) {
      size_t base = ((size_t)(xt * 64 + bg * 16 + ub)) * 2048 + dir * 1024 +
                    s * 16 + ucol;
      xp0 = xproj[base];
      xp1 = xproj[base + 256];
      xp2 = xproj[base + 512];
      xp3 = xproj[base + 768];
    }

    float acc[16];
#pragma unroll
    for (int b = 0; b < 16; ++b) acc[b] = 0.0f;

    if (st > 0) {
      if (tid < 16) {
        const int* fp = flags + fbase + tid;
        while (__hip_atomic_load(fp, __ATOMIC_RELAXED,
                                 __HIP_MEMORY_SCOPE_AGENT) < st) {
          __builtin_amdgcn_s_sleep(1);
        }
      }
      __syncthreads();  // B1: flag seen; prior-step hl reads all done
      int pt = dir ? (xt + 1) : (xt - 1);
      float* hsrc =
          h_all + ((size_t)(dir * Tn + pt) * 64 + bg * 16) * 256;
      // stage 2 granules via agent-scope loads (coherent past stale L1/L2)
      float* p = hsrc + sb * 256 + sq * 4;
      float4 v0, v1;
      v0.x = agent_ld(p + 0); v0.y = agent_ld(p + 1);
      v0.z = agent_ld(p + 2); v0.w = agent_ld(p + 3);
      v1.x = agent_ld(p + 4); v1.y = agent_ld(p + 5);
      v1.z = agent_ld(p + 6); v1.w = agent_ld(p + 7);
      *(float4*)&hl[sb * 256 + d0 * 4] = v0;
      *(float4*)&hl[sb * 256 + d1 * 4] = v1;
      __syncthreads();  // B2: hl ready
      // GEMV: h from LDS (8-way broadcast, XOR-permuted granules), W in regs
#pragma unroll
      for (int b = 0; b < 16; ++b) {
        float sacc = 0.0f;
#pragma unroll
        for (int j = 0; j < 8; ++j) {
          // granule gq = kc*8+j stored at kc*8 + (j^kc)
          float4 hv = *(const float4*)&hl[b * 256 + kc * 32 + (j ^ kc) * 4];
          sacc += w[j * 4 + 0] * hv.x + w[j * 4 + 1] * hv.y +
                  w[j * 4 + 2] * hv.z + w[j * 4 + 3] * hv.w;
        }
        acc[b] = sacc;
      }
    }

    // butterfly reduce over kc (lanes differing in tid&7)
#pragma unroll
    for (int m = 1; m < 8; m <<= 1) {
#pragma unroll
      for (int b = 0; b < 16; ++b) acc[b] += __shfl_xor(acc[b], m, 64);
    }
    // each lane now holds gate[row][0..15]; lane kc writes batches 2kc,2kc+1
    gl[row * 17 + 2 * kc] = acc[2 * kc];
    gl[row * 17 + 2 * kc + 1] = acc[2 * kc + 1];
    __syncthreads();  // B3: gl ready

    if (tid < 256) {
      float gi = gl[(0 * 16 + ucol) * 17 + ub] + xp0;
      float gf = gl[(1 * 16 + ucol) * 17 + ub] + xp1;
      float gg = gl[(2 * 16 + ucol) * 17 + ub] + xp2;
      float go = gl[(3 * 16 + ucol) * 17 + ub] + xp3;
      c_reg = sigm(gf) * c_reg + sigm(gi) * tanh_f(gg);
      float h = sigm(go) * tanh_f(c_reg);
      agent_st(&h_all[((size_t)(dir * Tn + xt) * 64 + bg * 16 + ub) * 256 +
                      s * 16 + ucol],
               h);
    }
    __syncthreads();  // B4: compiler drains vmcnt(0) before s_barrier ->
                      // all waves' h stores acked at coherence point
    if (tid == 0) {
      __hip_atomic_store(&flags[fbase + s], st + 1, __ATOMIC_RELAXED,
                         __HIP_MEMORY_SCOPE_AGENT);
    }
  }
}

// ---------------- K4: feats = concat(hf,hb) @ W_out^T + b_out ----------------
// one block per t; 256 thr = 64 b x 4 k-groups(5)
__global__ __launch_bounds__(256) void k_feats(const float* __restrict__ h_all,
                                               const float* __restrict__ Wout,
                                               const float* __restrict__ bout,
                                               float* __restrict__ feats) {
  __shared__ float Wl[20 * 512];   // 40KB
  __shared__ float hlf[64 * 256];  // 64KB, XOR-swizzled

  int tid = threadIdx.x;
  int t = blockIdx.x;
  for (int i = tid; i < 20 * 512; i += 256) Wl[i] = Wout[i];

  float acc[5] = {0, 0, 0, 0, 0};
  int b = tid & 63, kg5 = tid >> 6;
  int swz = b & 7;

  for (int d = 0; d < 2; ++d) {
    __syncthreads();
    const float* hsrc = h_all + ((size_t)(d * Tn + t)) * 64 * 256;
#pragma unroll 8
    for (int i = 0; i < 64; ++i) {
      int idx = i * 256 + tid;
      int hb = idx >> 8, k = idx & 255;
      hlf[hb * 256 + 4 * ((k >> 2) ^ (hb & 7)) + (k & 3)] = hsrc[idx];
    }
    __syncthreads();
    for (int jg = 0; jg < 64; ++jg) {
      float4 hv = *(const float4*)&hlf[b * 256 + 4 * (jg ^ swz)];
#pragma unroll
      for (int kk = 0; kk < 5; ++kk) {
        int krow = kg5 * 5 + kk;
        float4 wvv = *(const float4*)&Wl[krow * 512 + d * 256 + jg * 4];
        acc[kk] += hv.x * wvv.x + hv.y * wvv.y + hv.z * wvv.z + hv.w * wvv.w;
      }
    }
  }
#pragma unroll
  for (int kk = 0; kk < 5; ++kk) {
    int krow = kg5 * 5 + kk;
    feats[((size_t)b * Tn + t) * Kt + krow] = acc[kk] + bout[krow];
  }
}

// ---------------- K5: Viterbi decode, one wave per batch element -------------
__global__ __launch_bounds__(64) void k_viterbi(const float* __restrict__ feats,
                                                const float* __restrict__ trans,
                                                const int* __restrict__ length,
                                                float* __restrict__ out) {
  __shared__ float tr[400];
  __shared__ float fv[20];
  __shared__ float term[20];
  __shared__ unsigned char bps[256][20];

  int b = blockIdx.x;
  int lane = threadIdx.x;
  for (int i = lane; i < 400; i += 64) tr[i] = trans[i];
  if (lane < 20) fv[lane] = (lane == STARTt) ? 0.0f : NEGV;
  int len = length[b];
  __syncthreads();

  for (int t = 0; t < Tn; ++t) {
    float nf = 0.0f;
    int bp = 0;
    if (lane < 20) {
      if (t < len) {
        float vmax = -3.4e38f;
        int pb = 0;
#pragma unroll
        for (int p = 0; p < 20; ++p) {
          float v = fv[p] + tr[lane * 20 + p];
          if (v > vmax) { vmax = v; pb = p; }   // strict > == first-argmax
        }
        nf = vmax + feats[((size_t)b * Tn + t) * Kt + lane];
        bp = pb;
      } else {
        nf = fv[lane];
        bp = lane;
      }
    }
    __syncthreads();
    if (lane < 20) {
      fv[lane] = nf;
      bps[t][lane] = (unsigned char)bp;
    }
    __syncthreads();
  }

  if (lane < 20) term[lane] = fv[lane] + tr[STOPt * 20 + lane];
  __syncthreads();
  if (lane == 0) {
    float smax = term[0];
    int last = 0;
    for (int p = 1; p < 20; ++p)
      if (term[p] > smax) { smax = term[p]; last = p; }
    out[b] = smax;                     // viterbi score
    int tag = last;
    for (int t = Tn - 1; t >= 0; --t) {
      out[64 + b * Tn + t] = (float)tag;
      tag = bps[t][tag];
    }
  }
}

}  // namespace

extern "C" void kernel_launch(void* const* d_in, const int* in_sizes, int n_in,
                              void* d_out, int out_size, void* d_ws,
                              size_t ws_size, hipStream_t stream) {
  const int* sentence = (const int*)d_in[0];
  const int* length = (const int*)d_in[1];
  const float* table = (const float*)d_in[2];
  const float* w_ih_f = (const float*)d_in[3];
  const float* w_hh_f = (const float*)d_in[4];
  const float* b_f = (const float*)d_in[5];
  const float* w_ih_b = (const float*)d_in[6];
  const float* w_hh_b = (const float*)d_in[7];
  const float* b_b = (const float*)d_in[8];
  const float* W_out = (const float*)d_in[9];
  const float* b_out = (const float*)d_in[10];
  const float* trans = (const float*)d_in[11];
  float* out = (float*)d_out;

  // workspace layout (floats)
  float* ws = (float*)d_ws;
  float* xproj = ws;                               // 256*64*2048 = 33,554,432
  float* h_all = xproj + (size_t)Tn * Bn * 2048;   // 2*256*64*256 = 8,388,608
  float* Wt = h_all + (size_t)2 * Tn * Bn * HDn;   // 300*2048     =   614,400
  float* feats = Wt + (size_t)300 * 2048;          // 64*256*20    =   327,680
  int* flags = (int*)(feats + (size_t)Bn * Tn * Kt);  // 128 ints
  (void)ws_size; (void)in_sizes; (void)n_in; (void)out_size;

  k_init<<<dim3(1), dim3(128), 0, stream>>>(flags);
  k_wt<<<dim3(2400), dim3(256), 0, stream>>>(w_ih_f, w_ih_b, Wt);
  k_xproj<<<dim3(256, 16), dim3(256), 0, stream>>>(sentence, table, Wt, b_f,
                                                   b_b, xproj);
  k_lstm<<<dim3(128), dim3(512), 0, stream>>>(w_hh_f, w_hh_b, xproj, h_all,
                                              flags);
  k_feats<<<dim3(256), dim3(256), 0, stream>>>(h_all, W_out, b_out, feats);
  k_viterbi<<<dim3(64), dim3(64), 0, stream>>>(feats, trans, length, out);
}